// Round 5
// baseline (189.190 us; speedup 1.0000x reference)
//
#include <hip/hip_runtime.h>

#define BB 4096
#define TT 10
#define SS 301
#define HH 5
#define OO 3
#define NHALF (2048 * SS)   // 616448 == (B*S)/2 ; sample2 at b+2048, same s

typedef float f2 __attribute__((ext_vector_type(2)));

__device__ __forceinline__ f2 mk2(float a, float b){ f2 r; r.x = a; r.y = b; return r; }
__device__ __forceinline__ f2 sp2(float a){ f2 r; r.x = a; r.y = a; return r; }

// Forced VOP3P packed-fp32 (gfx90a+/gfx950). Operands are 64-bit VGPR pairs.
__device__ __forceinline__ f2 pk_fma(f2 a, f2 b, f2 c){
    f2 d;
    asm("v_pk_fma_f32 %0, %1, %2, %3" : "=v"(d) : "v"(a), "v"(b), "v"(c));
    return d;
}
__device__ __forceinline__ f2 pk_mul(f2 a, f2 b){
    f2 d;
    asm("v_pk_mul_f32 %0, %1, %2" : "=v"(d) : "v"(a), "v"(b));
    return d;
}
__device__ __forceinline__ f2 pk_add(f2 a, f2 b){
    f2 d;
    asm("v_pk_add_f32 %0, %1, %2" : "=v"(d) : "v"(a), "v"(b));
    return d;
}

// 1/d, d>0 (denominators in [1.3e5,3.6e6]): magic seed + 2 Newton (rel err ~6e-6).
// Seed+magic hardware-validated in round 4.
__device__ __forceinline__ f2 rcp2(f2 d){
    f2 nd = mk2(-d.x, -d.y);
    f2 y = mk2(__uint_as_float(0x7EF311C3u - __float_as_uint(d.x)),
               __uint_as_float(0x7EF311C3u - __float_as_uint(d.y)));
    y = pk_mul(y, pk_fma(nd, y, sp2(2.0f)));
    y = pk_mul(y, pk_fma(nd, y, sp2(2.0f)));
    return y;
}

// tanh Pade[7/6], clamped to [-4.8,4.8]; abs err <= ~1.4e-4. Validated round 4.
__device__ __forceinline__ f2 tanh2(f2 x){
    f2 t = __builtin_elementwise_min(__builtin_elementwise_max(x, sp2(-4.8f)), sp2(4.8f));
    f2 s = pk_mul(t, t);
    f2 nu = pk_mul(pk_fma(pk_fma(pk_add(s, sp2(378.0f)), s, sp2(17325.0f)), s, sp2(135135.0f)), t);
    f2 de = pk_fma(pk_fma(pk_fma(sp2(28.0f), s, sp2(3150.0f)), s, sp2(62370.0f)), s, sp2(135135.0f));
    return pk_mul(nu, rcp2(de));
}
// sigma(a) = 0.5 + 0.5*tanh(a/2)
__device__ __forceinline__ f2 sigmoid2(f2 a){
    return pk_fma(tanh2(pk_mul(a, sp2(0.5f))), sp2(0.5f), sp2(0.5f));
}

__global__ __launch_bounds__(256) void gru_kernel(
    const float* __restrict__ x,
    const float* __restrict__ w_ih,
    const float* __restrict__ w_hh,
    const float* __restrict__ b_ih,
    const float* __restrict__ b_hh,
    const float* __restrict__ fc_w,
    const float* __restrict__ fc_b,
    float* __restrict__ out)
{
    const int n = blockIdx.x * blockDim.x + threadIdx.x;   // 0 .. NHALF-1
    if (n >= NHALF) return;
    const int b = n / SS;          // 0 .. 2047
    const int s = n - b * SS;

    // Wave-uniform weights stay scalar -> SGPRs; scalar v_fma reads them directly.
    float wr[HH], wz[HH], wn[HH];
    float br_[HH], bz_[HH], bi_[HH], bh_[HH];
    float whr[HH][HH], whz[HH][HH], whn[HH][HH];

    #pragma unroll
    for (int j = 0; j < HH; ++j) {
        wr[j] = w_ih[j];
        wz[j] = w_ih[HH + j];
        wn[j] = w_ih[2 * HH + j];
        br_[j] = b_ih[j]        + b_hh[j];
        bz_[j] = b_ih[HH + j]   + b_hh[HH + j];
        bi_[j] = b_ih[2 * HH + j];
        bh_[j] = b_hh[2 * HH + j];
        #pragma unroll
        for (int k = 0; k < HH; ++k) {
            whr[j][k] = w_hh[j * HH + k];
            whz[j][k] = w_hh[(HH + j) * HH + k];
            whn[j][k] = w_hh[(2 * HH + j) * HH + k];
        }
    }

    // Preload x for both samples; each stream coalesced across the wave.
    const float* xp = x + (size_t)b * (TT * SS) + s;
    const size_t x2off = (size_t)2048 * TT * SS;
    float xtx[TT], xty[TT];
    #pragma unroll
    for (int t = 0; t < TT; ++t) { xtx[t] = xp[t * SS]; xty[t] = xp[t * SS + x2off]; }

    float hx[HH], hy[HH];
    #pragma unroll
    for (int j = 0; j < HH; ++j) { hx[j] = 0.0f; hy[j] = 0.0f; }

    #pragma unroll
    for (int t = 0; t < TT; ++t) {
        const float xvx = xtx[t], xvy = xty[t];
        float hnx[HH], hny[HH];
        #pragma unroll
        for (int j = 0; j < HH; ++j) {
            // scalar matvec, 2 samples (SGPR weight operands)
            float arx = __fmaf_rn(xvx, wr[j], br_[j]);
            float ary = __fmaf_rn(xvy, wr[j], br_[j]);
            float azx = __fmaf_rn(xvx, wz[j], bz_[j]);
            float azy = __fmaf_rn(xvy, wz[j], bz_[j]);
            float anx = __fmaf_rn(xvx, wn[j], bi_[j]);
            float any_ = __fmaf_rn(xvy, wn[j], bi_[j]);
            float ahx = bh_[j], ahy = bh_[j];
            #pragma unroll
            for (int k = 0; k < HH; ++k) {
                arx = __fmaf_rn(hx[k], whr[j][k], arx);
                ary = __fmaf_rn(hy[k], whr[j][k], ary);
                azx = __fmaf_rn(hx[k], whz[j][k], azx);
                azy = __fmaf_rn(hy[k], whz[j][k], azy);
                ahx = __fmaf_rn(hx[k], whn[j][k], ahx);
                ahy = __fmaf_rn(hy[k], whn[j][k], ahy);
            }
            // packed activations (constants only -> splat-once VGPR pairs)
            f2 r  = sigmoid2(mk2(arx, ary));
            f2 z  = sigmoid2(mk2(azx, azy));
            f2 nv = tanh2(pk_fma(r, mk2(ahx, ahy), mk2(anx, any_)));
            // h' = z*(h - n) + n  (scalar)
            hnx[j] = __fmaf_rn(z.x, hx[j] - nv.x, nv.x);
            hny[j] = __fmaf_rn(z.y, hy[j] - nv.y, nv.y);
        }
        #pragma unroll
        for (int j = 0; j < HH; ++j) { hx[j] = hnx[j]; hy[j] = hny[j]; }
    }

    // y = fc(h); out[(b*O + o)*S + s], second sample at b+2048.
    float* op = out + (size_t)b * (OO * SS) + s;
    const size_t o2off = (size_t)2048 * OO * SS;
    #pragma unroll
    for (int o = 0; o < OO; ++o) {
        float yx = fc_b[o], yy = fc_b[o];
        #pragma unroll
        for (int k = 0; k < HH; ++k) {
            yx = __fmaf_rn(fc_w[o * HH + k], hx[k], yx);
            yy = __fmaf_rn(fc_w[o * HH + k], hy[k], yy);
        }
        op[o * SS]         = yx;
        op[o * SS + o2off] = yy;
    }
}

extern "C" void kernel_launch(void* const* d_in, const int* in_sizes, int n_in,
                              void* d_out, int out_size, void* d_ws, size_t ws_size,
                              hipStream_t stream) {
    const float* x    = (const float*)d_in[0];
    const float* w_ih = (const float*)d_in[1];
    const float* w_hh = (const float*)d_in[2];
    const float* b_ih = (const float*)d_in[3];
    const float* b_hh = (const float*)d_in[4];
    const float* fc_w = (const float*)d_in[5];
    const float* fc_b = (const float*)d_in[6];
    float* out = (float*)d_out;

    const int block = 256;
    const int grid = NHALF / block;   // 2408 exactly
    gru_kernel<<<grid, block, 0, stream>>>(x, w_ih, w_hh, b_ih, b_hh, fc_w, fc_b, out);
}

// Round 6
// 160.115 us; speedup vs baseline: 1.1816x; 1.1816x over previous
//
#include <hip/hip_runtime.h>

#define BB 4096
#define TT 10
#define SS 301
#define HH 5
#define OO 3

// 1/d for d>0: magic seed + 2 Newton steps (rel err ~1.5e-6).
// Hardware-validated in rounds 4/5.
__device__ __forceinline__ float nrcp(float d){
    float y = __uint_as_float(0x7EF311C3u - __float_as_uint(d));
    y = y * __fmaf_rn(-d, y, 2.0f);
    y = y * __fmaf_rn(-d, y, 2.0f);
    return y;
}

// tanh Pade[7/6] (Lambert CF depth 7), arg clamped to [-4.8,4.8].
// Abs err <= ~1.4e-4 incl. clamp tail. Hardware-validated rounds 4/5.
__device__ __forceinline__ float tanh_pade(float x){
    float t = fminf(fmaxf(x, -4.8f), 4.8f);
    float s = t * t;
    float nu = __fmaf_rn(__fmaf_rn(s + 378.0f, s, 17325.0f), s, 135135.0f) * t;
    float de = __fmaf_rn(__fmaf_rn(__fmaf_rn(28.0f, s, 3150.0f), s, 62370.0f), s, 135135.0f);
    return nu * nrcp(de);
}

// sigma(a) where u = a/2 is supplied (0.5 folded into the weights):
// sigma = 0.5 + 0.5*tanh(u); the 0.5 is folded into the numerator coeffs.
__device__ __forceinline__ float sigmoid_half(float u){
    float t = fminf(fmaxf(u, -4.8f), 4.8f);
    float s = t * t;
    float nu = __fmaf_rn(__fmaf_rn(__fmaf_rn(0.5f, s, 189.0f), s, 8662.5f), s, 67567.5f) * t;
    float de = __fmaf_rn(__fmaf_rn(__fmaf_rn(28.0f, s, 3150.0f), s, 62370.0f), s, 135135.0f);
    return __fmaf_rn(nu, nrcp(de), 0.5f);
}

__global__ __launch_bounds__(256) void gru_kernel(
    const float* __restrict__ x,
    const float* __restrict__ w_ih,
    const float* __restrict__ w_hh,
    const float* __restrict__ b_ih,
    const float* __restrict__ b_hh,
    const float* __restrict__ fc_w,
    const float* __restrict__ fc_b,
    float* __restrict__ out)
{
    const int n = blockIdx.x * blockDim.x + threadIdx.x;
    const int b = n / SS;
    const int s = n - b * SS;
    if (b >= BB) return;

    // Wave-uniform weights -> SGPRs. r,z gate weights pre-halved (sigma takes a/2).
    float wr[HH], wz[HH], wn[HH];
    float br_[HH], bz_[HH], bi_[HH], bh_[HH];
    float whr[HH][HH], whz[HH][HH], whn[HH][HH];

    #pragma unroll
    for (int j = 0; j < HH; ++j) {
        wr[j] = 0.5f * w_ih[j];
        wz[j] = 0.5f * w_ih[HH + j];
        wn[j] = w_ih[2 * HH + j];
        br_[j] = 0.5f * (b_ih[j]      + b_hh[j]);
        bz_[j] = 0.5f * (b_ih[HH + j] + b_hh[HH + j]);
        bi_[j] = b_ih[2 * HH + j];
        bh_[j] = b_hh[2 * HH + j];
        #pragma unroll
        for (int k = 0; k < HH; ++k) {
            whr[j][k] = 0.5f * w_hh[j * HH + k];
            whz[j][k] = 0.5f * w_hh[(HH + j) * HH + k];
            whn[j][k] = w_hh[(2 * HH + j) * HH + k];
        }
    }

    // Preload the 10 inputs (coalesced across the wave per t).
    float xt[TT];
    const float* xp = x + (size_t)b * (TT * SS) + s;
    #pragma unroll
    for (int t = 0; t < TT; ++t) xt[t] = xp[t * SS];

    float h[HH];
    #pragma unroll
    for (int j = 0; j < HH; ++j) h[j] = 0.0f;

    #pragma unroll
    for (int t = 0; t < TT; ++t) {
        const float xv = xt[t];
        float hn[HH];
        #pragma unroll
        for (int j = 0; j < HH; ++j) {
            float ur  = __fmaf_rn(xv, wr[j], br_[j]);   // a_r / 2
            float uz  = __fmaf_rn(xv, wz[j], bz_[j]);   // a_z / 2
            float ain = __fmaf_rn(xv, wn[j], bi_[j]);
            float ahn = bh_[j];
            #pragma unroll
            for (int k = 0; k < HH; ++k) {
                ur  = __fmaf_rn(whr[j][k], h[k], ur);
                uz  = __fmaf_rn(whz[j][k], h[k], uz);
                ahn = __fmaf_rn(whn[j][k], h[k], ahn);
            }
            float r  = sigmoid_half(ur);
            float z  = sigmoid_half(uz);
            float nv = tanh_pade(__fmaf_rn(r, ahn, ain));
            hn[j] = __fmaf_rn(z, h[j] - nv, nv);        // (1-z)n + z h
        }
        #pragma unroll
        for (int j = 0; j < HH; ++j) h[j] = hn[j];
    }

    // y = fc(h); out[(b*O + o)*S + s]
    float* op = out + (size_t)b * (OO * SS) + s;
    #pragma unroll
    for (int o = 0; o < OO; ++o) {
        float y = fc_b[o];
        #pragma unroll
        for (int k = 0; k < HH; ++k) y = __fmaf_rn(fc_w[o * HH + k], h[k], y);
        op[o * SS] = y;
    }
}

extern "C" void kernel_launch(void* const* d_in, const int* in_sizes, int n_in,
                              void* d_out, int out_size, void* d_ws, size_t ws_size,
                              hipStream_t stream) {
    const float* x    = (const float*)d_in[0];
    const float* w_ih = (const float*)d_in[1];
    const float* w_hh = (const float*)d_in[2];
    const float* b_ih = (const float*)d_in[3];
    const float* b_hh = (const float*)d_in[4];
    const float* fc_w = (const float*)d_in[5];
    const float* fc_b = (const float*)d_in[6];
    float* out = (float*)d_out;

    const int N = BB * SS;                 // 1,232,896
    const int block = 256;
    const int grid = (N + block - 1) / block;  // 4816 exactly
    gru_kernel<<<grid, block, 0, stream>>>(x, w_ih, w_hh, b_ih, b_hh, fc_w, fc_b, out);
}